// Round 2
// baseline (420.420 us; speedup 1.0000x reference)
//
#include <hip/hip_runtime.h>
#include <hip/hip_bf16.h>

#define EMBED 1024
#define THREE_EMBED 3072
#define NHEAD 16
#define HDIM 64
#define MTOT 16384
#define LTOT 16383

typedef __attribute__((ext_vector_type(8))) short bf16x8;
typedef __attribute__((ext_vector_type(4))) float f32x4;

__device__ __forceinline__ unsigned short f2b(float f) {
  union { float f; unsigned u; } v; v.f = f;
  unsigned r = v.u + 0x7fffu + ((v.u >> 16) & 1u);
  return (unsigned short)(r >> 16);
}
__device__ __forceinline__ float b2f(unsigned short h) {
  union { unsigned u; float f; } v; v.u = ((unsigned)h) << 16;
  return v.f;
}

__device__ __forceinline__ void gload16(const void* g, void* l) {
  __builtin_amdgcn_global_load_lds(
      (const __attribute__((address_space(1))) void*)g,
      (__attribute__((address_space(3))) void*)l, 16, 0, 0);
}

#define BARRIER() asm volatile("s_barrier" ::: "memory")

// ---------------------------------------------------------------------------
// cast pass: x (+padding) -> xb bf16; qkv_w -> wqb bf16; inv[kvi[i]] = i
// ---------------------------------------------------------------------------
__global__ __launch_bounds__(256) void cast_inputs(
    const float* __restrict__ x, const float* __restrict__ padding,
    const float* __restrict__ wq, const int* __restrict__ kvi,
    unsigned short* __restrict__ xb, unsigned short* __restrict__ wqb,
    int* __restrict__ inv)
{
  const int NX = MTOT * EMBED / 8;
  const int NQ = THREE_EMBED * EMBED / 8;
  const int total = NX + NQ;
  int g = blockIdx.x * 256 + threadIdx.x;
  const int stride = gridDim.x * 256;
  for (; g < total + MTOT; g += stride) {
    if (g >= total) {
      int i = g - total;
      inv[kvi[i]] = i;
      continue;
    }
    const float* src;
    unsigned short* dst;
    if (g < NX) {
      size_t e = (size_t)g * 8;
      int row = (int)(e >> 10);
      src = (row < LTOT) ? (x + e) : (padding + (e - (size_t)LTOT * 1024));
      dst = xb + e;
    } else {
      size_t e = (size_t)(g - NX) * 8;
      src = wq + e;
      dst = wqb + e;
    }
    float4 a = *(const float4*)src;
    float4 b = *(const float4*)(src + 4);
    ushort4 u0, u1;
    u0.x = f2b(a.x); u0.y = f2b(a.y); u0.z = f2b(a.z); u0.w = f2b(a.w);
    u1.x = f2b(b.x); u1.y = f2b(b.y); u1.z = f2b(b.z); u1.w = f2b(b.w);
    *(ushort4*)dst = u0;
    *(ushort4*)(dst + 4) = u1;
  }
}

// ---------------------------------------------------------------------------
// 256x256 8-phase GEMM (T2+T3+T4+T5), C = A @ B^T + bias.
// 512 threads = 8 waves as 2(M)x4(N); per-wave output 128x64; BK=64.
// Round-2 change: main loop is a 2-K-tile unrolled body (m201's actual
// "8 phases / 2 K-tiles per iter") so buffer parity P is COMPILE-TIME ->
// ds_read bases are immediates and the scheduler can pipeline across the
// tile boundary. Barrier/vmcnt schedule identical to round 1:
//   p0: read B(8)+Aq0; stage (t+1)A0 | BAR | MFMA q0 | BAR
//   p1: read Aq1;      stage (t+1)A1 | BAR | MFMA q1 | BAR
//   p2: read Aq2;      stage (t+2)B0 | BAR | MFMA q2 | BAR
//   p3: read Aq3;      stage (t+2)B1 | BAR | MFMA q3 | vmcnt(4) | BAR
// vmcnt(4) leaves (t+2)'s B pair in flight (counted, never 0 mid-loop).
// EPI=0: bias + scatter via inv[] to head-major qkvh bf16 (gemm_qkv).
// EPI=1: bias + fp32 row-scatter via kvi[] with kvi<LTOT guard (gemm_proj;
//        A is read in window-permuted order, so the permutation is applied
//        at the OUTPUT side as full-line 64B fp32 chunks — no RMW).
// ---------------------------------------------------------------------------
template <int EPI>
__global__ __launch_bounds__(512, 2) void gemm256(
    const unsigned short* __restrict__ A, const unsigned short* __restrict__ B,
    const float* __restrict__ bias, const int* __restrict__ idx,
    unsigned short* __restrict__ outb, float* __restrict__ outf)
{
  __shared__ __align__(16) unsigned short lds[65536];  // 128 KiB
  const int t = threadIdx.x;
  const int lane = t & 63, wid = t >> 6;
  const int l15 = lane & 15, quad = lane >> 4;
  const int wr = wid >> 2, wc = wid & 3;
  const int bm = blockIdx.x, bn = blockIdx.y;

  // staging: linear LDS dest + inverse-swizzled global source (rule #21)
  const int srow = wid * 8 + (lane >> 3);
  const int scol = ((lane & 7) ^ (lane >> 3)) * 8;
  const unsigned short* gA = A + (size_t)(bm * 256 + srow) * EMBED + scol;
  const unsigned short* gB = B + (size_t)(bn * 256 + srow) * EMBED + scol;

  auto stA = [&](int p, int R0, int kt) {
    const unsigned short* g = gA + (size_t)R0 * EMBED + kt * 64;
    char* d = (char*)lds + p * 32768 + R0 * 128 + wid * 1024;
    gload16(g, d);
    gload16(g + (size_t)64 * EMBED, d + 8192);
  };
  auto stB = [&](int p, int R0, int kt) {
    const unsigned short* g = gB + (size_t)R0 * EMBED + kt * 64;
    char* d = (char*)lds + 65536 + p * 32768 + R0 * 128 + wid * 1024;
    gload16(g, d);
    gload16(g + (size_t)64 * EMBED, d + 8192);
  };

  const int aOff = (wr * 128 + l15) * 64;
  const int bOff = (wc * 64 + l15) * 64;
  const int swz0 = (quad ^ (l15 & 7)) * 8;
  const int swz1 = ((quad + 4) ^ (l15 & 7)) * 8;

  f32x4 acc[8][4];
#pragma unroll
  for (int i = 0; i < 8; ++i)
#pragma unroll
    for (int j = 0; j < 4; ++j) acc[i][j] = (f32x4){0.f, 0.f, 0.f, 0.f};

  // prologue: tile0 (A0,A1,B0,B1) + tile1 (B0,B1); vmcnt(4) keeps tile1's
  // B pair in flight.
  stA(0, 0, 0); stA(0, 128, 0); stB(0, 0, 0); stB(0, 128, 0);
  stB(1, 0, 1); stB(1, 128, 1);
  asm volatile("s_waitcnt vmcnt(4)" ::: "memory");
  BARRIER();

#define MFMA16(m0, m1)                                                       \
  do {                                                                       \
    _Pragma("unroll") for (int nt = 0; nt < 4; ++nt)                         \
        acc[m0][nt] = __builtin_amdgcn_mfma_f32_16x16x32_bf16(               \
            a00, b0[nt], acc[m0][nt], 0, 0, 0);                              \
    _Pragma("unroll") for (int nt = 0; nt < 4; ++nt)                         \
        acc[m1][nt] = __builtin_amdgcn_mfma_f32_16x16x32_bf16(               \
            a10, b0[nt], acc[m1][nt], 0, 0, 0);                              \
    _Pragma("unroll") for (int nt = 0; nt < 4; ++nt)                         \
        acc[m0][nt] = __builtin_amdgcn_mfma_f32_16x16x32_bf16(               \
            a01, b1[nt], acc[m0][nt], 0, 0, 0);                              \
    _Pragma("unroll") for (int nt = 0; nt < 4; ++nt)                         \
        acc[m1][nt] = __builtin_amdgcn_mfma_f32_16x16x32_bf16(               \
            a11, b1[nt], acc[m1][nt], 0, 0, 0);                              \
  } while (0)

  // One K-tile with compile-time parity P. STA/STB/WCNT are literals.
#define TILE(P, KT, STA, STB, WCNT)                                          \
  {                                                                          \
    const unsigned short* Ab = lds + (P) * 16384 + aOff;                     \
    const unsigned short* Bb = lds + 32768 + (P) * 16384 + bOff;             \
    bf16x8 b0[4], b1[4];                                                     \
    { /* phase 0 */                                                          \
      _Pragma("unroll") for (int nt = 0; nt < 4; ++nt) {                     \
        b0[nt] = *(const bf16x8*)(Bb + nt * 1024 + swz0);                    \
        b1[nt] = *(const bf16x8*)(Bb + nt * 1024 + swz1);                    \
      }                                                                      \
      bf16x8 a00 = *(const bf16x8*)(Ab + 0 * 1024 + swz0);                   \
      bf16x8 a01 = *(const bf16x8*)(Ab + 0 * 1024 + swz1);                   \
      bf16x8 a10 = *(const bf16x8*)(Ab + 1 * 1024 + swz0);                   \
      bf16x8 a11 = *(const bf16x8*)(Ab + 1 * 1024 + swz1);                   \
      if (STA) stA((P) ^ 1, 0, (KT) + 1);                                    \
      BARRIER();                                                             \
      __builtin_amdgcn_s_setprio(1);                                         \
      MFMA16(0, 1);                                                          \
      __builtin_amdgcn_s_setprio(0);                                         \
      BARRIER();                                                             \
    }                                                                        \
    { /* phase 1 */                                                          \
      bf16x8 a00 = *(const bf16x8*)(Ab + 2 * 1024 + swz0);                   \
      bf16x8 a01 = *(const bf16x8*)(Ab + 2 * 1024 + swz1);                   \
      bf16x8 a10 = *(const bf16x8*)(Ab + 3 * 1024 + swz0);                   \
      bf16x8 a11 = *(const bf16x8*)(Ab + 3 * 1024 + swz1);                   \
      if (STA) stA((P) ^ 1, 128, (KT) + 1);                                  \
      BARRIER();                                                             \
      __builtin_amdgcn_s_setprio(1);                                         \
      MFMA16(2, 3);                                                          \
      __builtin_amdgcn_s_setprio(0);                                         \
      BARRIER();                                                             \
    }                                                                        \
    { /* phase 2 */                                                          \
      bf16x8 a00 = *(const bf16x8*)(Ab + 4 * 1024 + swz0);                   \
      bf16x8 a01 = *(const bf16x8*)(Ab + 4 * 1024 + swz1);                   \
      bf16x8 a10 = *(const bf16x8*)(Ab + 5 * 1024 + swz0);                   \
      bf16x8 a11 = *(const bf16x8*)(Ab + 5 * 1024 + swz1);                   \
      if (STB) stB((P), 0, (KT) + 2);                                        \
      BARRIER();                                                             \
      __builtin_amdgcn_s_setprio(1);                                         \
      MFMA16(4, 5);                                                          \
      __builtin_amdgcn_s_setprio(0);                                         \
      BARRIER();                                                             \
    }                                                                        \
    { /* phase 3 */                                                          \
      bf16x8 a00 = *(const bf16x8*)(Ab + 6 * 1024 + swz0);                   \
      bf16x8 a01 = *(const bf16x8*)(Ab + 6 * 1024 + swz1);                   \
      bf16x8 a10 = *(const bf16x8*)(Ab + 7 * 1024 + swz0);                   \
      bf16x8 a11 = *(const bf16x8*)(Ab + 7 * 1024 + swz1);                   \
      if (STB) stB((P), 128, (KT) + 2);                                      \
      BARRIER();                                                             \
      __builtin_amdgcn_s_setprio(1);                                         \
      MFMA16(6, 7);                                                          \
      __builtin_amdgcn_s_setprio(0);                                         \
      if ((WCNT) == 4) asm volatile("s_waitcnt vmcnt(4)" ::: "memory");      \
      if ((WCNT) == 0) asm volatile("s_waitcnt vmcnt(0)" ::: "memory");      \
      BARRIER();                                                             \
    }                                                                        \
  }

#pragma unroll 1
  for (int t2 = 0; t2 < 7; ++t2) {
    const int kt = t2 * 2;
    TILE(0, kt, 1, 1, 4);
    TILE(1, kt + 1, 1, 1, 4);
  }
  // tail: tile 14 stages tile 15's A then drains; tile 15 computes clean.
  TILE(0, 14, 1, 0, 0);
  TILE(1, 15, 0, 0, -1);
#undef TILE
#undef MFMA16

  // epilogue
  float bv[4];
#pragma unroll
  for (int nt = 0; nt < 4; ++nt)
    bv[nt] = bias[bn * 256 + wc * 64 + nt * 16 + l15];
  if constexpr (EPI == 0) {
    const int hh = bn * 4 + wc;  // wave's 64-col span == one (part,head) slot
    unsigned short* buf = outb + (size_t)hh * (MTOT * HDIM);
#pragma unroll
    for (int mt = 0; mt < 8; ++mt) {
#pragma unroll
      for (int reg = 0; reg < 4; ++reg) {
        int row = bm * 256 + wr * 128 + mt * 16 + quad * 4 + reg;
        int i = idx[row];  // inv[]
#pragma unroll
        for (int nt = 0; nt < 4; ++nt)
          buf[(size_t)i * HDIM + nt * 16 + l15] =
              f2b(acc[mt][nt][reg] + bv[nt]);
      }
    }
  } else {
    const int col = bn * 256 + wc * 64;
#pragma unroll
    for (int mt = 0; mt < 8; ++mt) {
#pragma unroll
      for (int reg = 0; reg < 4; ++reg) {
        int i = bm * 256 + wr * 128 + mt * 16 + quad * 4 + reg;
        int orow = idx[i];  // kvi[]
        if (orow < LTOT) {
#pragma unroll
          for (int nt = 0; nt < 4; ++nt)
            outf[(size_t)orow * EMBED + col + nt * 16 + l15] =
                acc[mt][nt][reg] + bv[nt];
        }
      }
    }
  }
}

// ---------------------------------------------------------------------------
// rope_qk: in-place RoPE on qkvh head-slots 0..31 (Q scaled by 0.125).
// ---------------------------------------------------------------------------
__global__ __launch_bounds__(256) void rope_qk(
    const float* __restrict__ rope_cos, const float* __restrict__ rope_sin,
    unsigned short* __restrict__ qkvh)
{
  int g = blockIdx.x * 256 + threadIdx.x;
  int dc = g & 3;
  int i  = (g >> 2) & (MTOT - 1);
  int hh = g >> 16;
  unsigned short* p = qkvh + ((size_t)hh * MTOT + i) * HDIM;
  bf16x8 lo = *(const bf16x8*)(p + dc * 8);
  bf16x8 hi = *(const bf16x8*)(p + 32 + dc * 8);
  const float* cp = rope_cos + (size_t)i * HDIM + dc * 8;
  const float* sp = rope_sin + (size_t)i * HDIM + dc * 8;
  float cl[8], ch[8], sl[8], sh[8];
  *(float4*)(cl)     = *(const float4*)(cp);
  *(float4*)(cl + 4) = *(const float4*)(cp + 4);
  *(float4*)(ch)     = *(const float4*)(cp + 32);
  *(float4*)(ch + 4) = *(const float4*)(cp + 36);
  *(float4*)(sl)     = *(const float4*)(sp);
  *(float4*)(sl + 4) = *(const float4*)(sp + 4);
  *(float4*)(sh)     = *(const float4*)(sp + 32);
  *(float4*)(sh + 4) = *(const float4*)(sp + 36);
  const float sc = (hh < 16) ? 0.125f : 1.0f;
  bf16x8 olo, ohi;
#pragma unroll
  for (int j = 0; j < 8; ++j) {
    float a = b2f((unsigned short)lo[j]);
    float b = b2f((unsigned short)hi[j]);
    olo[j] = (short)f2b((a * cl[j] - b * sl[j]) * sc);
    ohi[j] = (short)f2b((b * ch[j] + a * sh[j]) * sc);
  }
  *(bf16x8*)(p + dc * 8) = olo;
  *(bf16x8*)(p + 32 + dc * 8) = ohi;
}

// ---------------------------------------------------------------------------
// cast_w: proj_w fp32 -> bf16, into the (now dead) Q region of qkvh.
// ---------------------------------------------------------------------------
__global__ __launch_bounds__(256) void cast_w(
    const float* __restrict__ w, unsigned short* __restrict__ wb)
{
  int g = blockIdx.x * 256 + threadIdx.x;
  size_t e = (size_t)g * 8;
  float4 a = *(const float4*)(w + e);
  float4 b = *(const float4*)(w + e + 4);
  ushort4 u0, u1;
  u0.x = f2b(a.x); u0.y = f2b(a.y); u0.z = f2b(a.z); u0.w = f2b(a.w);
  u1.x = f2b(b.x); u1.y = f2b(b.y); u1.z = f2b(b.z); u1.w = f2b(b.w);
  *(ushort4*)(wb + e) = u0;
  *(ushort4*)(wb + e + 4) = u1;
}

// ---------------------------------------------------------------------------
// Attention: one block per (window, head). Round-2 change: output is
// written in WINDOW-PERMUTED order (ow[i][h*64+d], i = this block's own
// contiguous rows) — fully coalesced, no scatter, no RMW amplification.
// The kvi permutation moved to gemm_proj's fp32 epilogue.
// ---------------------------------------------------------------------------
__global__ __launch_bounds__(256, 4) void attn(
    const unsigned short* __restrict__ qkvh,
    unsigned short* __restrict__ ow)
{
  __shared__ __align__(16) unsigned short sK[128 * 64];
  __shared__ __align__(16) unsigned short sV[64 * 128];
  __shared__ __align__(16) unsigned short sP[4][16 * 40];

  const int t = threadIdx.x;
  const int lane = t & 63, wid = t >> 6;
  const int l15 = lane & 15, quad = lane >> 4;
  const int wwin = blockIdx.x >> 4;
  const int h = blockIdx.x & 15;

  const unsigned short* Qh = qkvh + (size_t)h * (MTOT * HDIM);
  const unsigned short* Kh = qkvh + (size_t)(16 + h) * (MTOT * HDIM);
  const unsigned short* Vh = qkvh + (size_t)(32 + h) * (MTOT * HDIM);

  f32x4 accO[4][4];
  float mrow[4][4], lrow[4][4];
#pragma unroll
  for (int qt = 0; qt < 4; ++qt) {
#pragma unroll
    for (int nt = 0; nt < 4; ++nt) accO[qt][nt] = (f32x4){0.f, 0.f, 0.f, 0.f};
#pragma unroll
    for (int reg = 0; reg < 4; ++reg) { mrow[qt][reg] = -1e30f; lrow[qt][reg] = 0.f; }
  }

  bf16x8 qa[4][2];
#pragma unroll
  for (int qt = 0; qt < 4; ++qt) {
    int i = wwin * 256 + wid * 64 + qt * 16 + l15;
    const unsigned short* qp = Qh + (size_t)i * HDIM;
    qa[qt][0] = *(const bf16x8*)(qp + quad * 8);
    qa[qt][1] = *(const bf16x8*)(qp + 32 + quad * 8);
  }

  for (int half = 0; half < 2; ++half) {
    __syncthreads();
    {
      int key = t >> 1, hx = t & 1;
      int i = wwin * 256 + half * 128 + key;
      const unsigned short* kp = Kh + (size_t)i * HDIM + hx * 32;
#pragma unroll
      for (int cc = 0; cc < 4; ++cc) {
        int c = hx * 4 + cc;
        uint4 kv = *(const uint4*)(kp + cc * 8);
        *(uint4*)(sK + key * 64 + ((c ^ (key & 7)) * 8)) = kv;
      }
      const unsigned short* vp = Vh + (size_t)i * HDIM + hx * 32;
      int kc3 = key >> 3, k7 = key & 7;
#pragma unroll
      for (int c = 0; c < 4; ++c) {
        bf16x8 va = *(const bf16x8*)(vp + c * 8);
#pragma unroll
        for (int j = 0; j < 8; ++j) {
          int d = hx * 32 + c * 8 + j;
          sV[d * 128 + ((kc3 ^ (d & 7)) * 8) + k7] = (unsigned short)va[j];
        }
      }
    }
    __syncthreads();

#pragma unroll
    for (int qt = 0; qt < 4; ++qt) {
      f32x4 accS[8];
#pragma unroll
      for (int nt = 0; nt < 8; ++nt) accS[nt] = (f32x4){0.f, 0.f, 0.f, 0.f};
#pragma unroll
      for (int ks = 0; ks < 2; ++ks) {
#pragma unroll
        for (int nt = 0; nt < 8; ++nt) {
          int key = nt * 16 + l15;
          bf16x8 bk = *(const bf16x8*)(
              sK + key * 64 + (((ks * 4 + quad) ^ (key & 7)) * 8));
          accS[nt] = __builtin_amdgcn_mfma_f32_16x16x32_bf16(
              qa[qt][ks], bk, accS[nt], 0, 0, 0);
        }
      }
#pragma unroll
      for (int reg = 0; reg < 4; ++reg) {
        float mx = accS[0][reg];
#pragma unroll
        for (int nt = 1; nt < 8; ++nt) mx = fmaxf(mx, accS[nt][reg]);
#pragma unroll
        for (int off = 1; off < 16; off <<= 1)
          mx = fmaxf(mx, __shfl_xor(mx, off, 64));
        float mold = mrow[qt][reg];
        float mnew = fmaxf(mold, mx);
        float alpha = __expf(mold - mnew);
        mrow[qt][reg] = mnew;
        float ls = 0.f;
#pragma unroll
        for (int nt = 0; nt < 8; ++nt) {
          float p = __expf(accS[nt][reg] - mnew);
          accS[nt][reg] = p;
          ls += p;
        }
#pragma unroll
        for (int off = 1; off < 16; off <<= 1) ls += __shfl_xor(ls, off, 64);
        lrow[qt][reg] = lrow[qt][reg] * alpha + ls;
#pragma unroll
        for (int nt = 0; nt < 4; ++nt) accO[qt][nt][reg] *= alpha;
      }
#pragma unroll
      for (int kc = 0; kc < 4; ++kc) {
#pragma unroll
        for (int nt2 = 0; nt2 < 2; ++nt2) {
#pragma unroll
          for (int reg = 0; reg < 4; ++reg) {
            sP[wid][(quad * 4 + reg) * 40 + nt2 * 16 + l15] =
                f2b(accS[kc * 2 + nt2][reg]);
          }
        }
        bf16x8 pa = *(const bf16x8*)(&sP[wid][l15 * 40 + quad * 8]);
#pragma unroll
        for (int nt = 0; nt < 4; ++nt) {
          int d = nt * 16 + l15;
          bf16x8 bv = *(const bf16x8*)(
              sV + d * 128 + (((kc * 4 + quad) ^ (d & 7)) * 8));
          accO[qt][nt] = __builtin_amdgcn_mfma_f32_16x16x32_bf16(
              pa, bv, accO[qt][nt], 0, 0, 0);
        }
      }
    }
  }

  // coalesced write: block's own contiguous permuted rows, head column slab
#pragma unroll
  for (int qt = 0; qt < 4; ++qt) {
#pragma unroll
    for (int reg = 0; reg < 4; ++reg) {
      int i = wwin * 256 + wid * 64 + qt * 16 + quad * 4 + reg;
      float inv = 1.0f / lrow[qt][reg];
      unsigned short* op = ow + (size_t)i * EMBED + h * HDIM;
#pragma unroll
      for (int nt = 0; nt < 4; ++nt) {
        op[nt * 16 + l15] = f2b(accO[qt][nt][reg] * inv);
      }
    }
  }
}

// ---------------------------------------------------------------------------
extern "C" void kernel_launch(void* const* d_in, const int* in_sizes, int n_in,
                              void* d_out, int out_size, void* d_ws, size_t ws_size,
                              hipStream_t stream) {
  const float* x        = (const float*)d_in[0];
  const float* qkv_w    = (const float*)d_in[1];
  const float* qkv_b    = (const float*)d_in[2];
  const float* proj_w   = (const float*)d_in[3];
  const float* proj_b   = (const float*)d_in[4];
  const float* padding  = (const float*)d_in[5];
  const float* rope_cos = (const float*)d_in[6];
  const float* rope_sin = (const float*)d_in[7];
  const int*   kvi      = (const int*)d_in[8];

  // ws layout (134.2 MB, proven safe):
  //   [0, 100.66M):       qkvh — head-major, window-permuted [48][16384][64]
  //                       bf16; Q region doubles as wpb after attn.
  //   [100.66M, +33.55M): xb (cast+gemm_qkv) then ow (attn output,
  //                       window-permuted [16384][1024] bf16, gemm_proj A)
  // d_out scratch: head: wqb (6.3 MB); tail: inv (64 KB int32) — both read
  // only by gemm_qkv, which completes before gemm_proj (stream order).
  unsigned short* qkvh = (unsigned short*)d_ws;
  unsigned short* R    = (unsigned short*)((char*)d_ws +
                            (size_t)MTOT * THREE_EMBED * 2);
  unsigned short* xb = R;
  unsigned short* ow = R;
  unsigned short* wqb = (unsigned short*)d_out;
  unsigned short* wpb = qkvh;  // Q region, dead after attn
  int* inv = (int*)((char*)d_out + (size_t)LTOT * EMBED * 4 - (size_t)MTOT * 4);
  float* out = (float*)d_out;

  cast_inputs<<<4096, 256, 0, stream>>>(x, padding, qkv_w, kvi, xb, wqb, inv);
  gemm256<0><<<dim3(64, 12), 512, 0, stream>>>(xb, wqb, qkv_b, inv, qkvh,
                                               nullptr);
  rope_qk<<<8192, 256, 0, stream>>>(rope_cos, rope_sin, qkvh);
  attn<<<dim3(64 * 16), 256, 0, stream>>>(qkvh, ow);
  cast_w<<<512, 256, 0, stream>>>(proj_w, wpb);
  gemm256<1><<<dim3(64, 4), 512, 0, stream>>>(ow, wpb, proj_b, kvi, nullptr,
                                              out);
}

// Round 4
// 401.590 us; speedup vs baseline: 1.0469x; 1.0469x over previous
//
#include <hip/hip_runtime.h>
#include <hip/hip_bf16.h>

#define EMBED 1024
#define THREE_EMBED 3072
#define NHEAD 16
#define HDIM 64
#define MTOT 16384
#define LTOT 16383

typedef __attribute__((ext_vector_type(8))) short bf16x8;
typedef __attribute__((ext_vector_type(4))) float f32x4;

__device__ __forceinline__ unsigned short f2b(float f) {
  union { float f; unsigned u; } v; v.f = f;
  unsigned r = v.u + 0x7fffu + ((v.u >> 16) & 1u);
  return (unsigned short)(r >> 16);
}
__device__ __forceinline__ float b2f(unsigned short h) {
  union { unsigned u; float f; } v; v.u = ((unsigned)h) << 16;
  return v.f;
}

__device__ __forceinline__ void gload16(const void* g, void* l) {
  __builtin_amdgcn_global_load_lds(
      (const __attribute__((address_space(1))) void*)g,
      (__attribute__((address_space(3))) void*)l, 16, 0, 0);
}

#define BARRIER() asm volatile("s_barrier" ::: "memory")

// ---------------------------------------------------------------------------
// cast pass: x (+padding) -> xb bf16; qkv_w -> wqb bf16; inv[kvi[i]] = i
// ---------------------------------------------------------------------------
__global__ __launch_bounds__(256) void cast_inputs(
    const float* __restrict__ x, const float* __restrict__ padding,
    const float* __restrict__ wq, const int* __restrict__ kvi,
    unsigned short* __restrict__ xb, unsigned short* __restrict__ wqb,
    int* __restrict__ inv)
{
  const int NX = MTOT * EMBED / 8;
  const int NQ = THREE_EMBED * EMBED / 8;
  const int total = NX + NQ;
  int g = blockIdx.x * 256 + threadIdx.x;
  const int stride = gridDim.x * 256;
  for (; g < total + MTOT; g += stride) {
    if (g >= total) {
      int i = g - total;
      inv[kvi[i]] = i;
      continue;
    }
    const float* src;
    unsigned short* dst;
    if (g < NX) {
      size_t e = (size_t)g * 8;
      int row = (int)(e >> 10);
      src = (row < LTOT) ? (x + e) : (padding + (e - (size_t)LTOT * 1024));
      dst = xb + e;
    } else {
      size_t e = (size_t)(g - NX) * 8;
      src = wq + e;
      dst = wqb + e;
    }
    float4 a = *(const float4*)src;
    float4 b = *(const float4*)(src + 4);
    ushort4 u0, u1;
    u0.x = f2b(a.x); u0.y = f2b(a.y); u0.z = f2b(a.z); u0.w = f2b(a.w);
    u1.x = f2b(b.x); u1.y = f2b(b.y); u1.z = f2b(b.z); u1.w = f2b(b.w);
    *(ushort4*)dst = u0;
    *(ushort4*)(dst + 4) = u1;
  }
}

// ---------------------------------------------------------------------------
// 256x256 8-phase GEMM (T2+T3+T4+T5), C = A @ B^T + bias.
// 512 threads = 8 waves as 2(M)x4(N); per-wave output 128x64; BK=64.
// Main loop: 2-K-tile unrolled body, compile-time buffer parity.
//   p0: read B(8)+Aq0; stage (t+1)A0 | BAR | MFMA q0 | BAR
//   p1: read Aq1;      stage (t+1)A1 | BAR | MFMA q1 | BAR
//   p2: read Aq2;      stage (t+2)B0 | BAR | MFMA q2 | BAR
//   p3: read Aq3;      stage (t+2)B1 | BAR | MFMA q3 | vmcnt(4) | BAR
// EPI=0: bias + scatter via inv[] to head-major qkvh bf16 (gemm_qkv).
// EPI=1: bias + fp32 row-scatter via kvi[] with kvi<LTOT guard (gemm_proj).
// ---------------------------------------------------------------------------
template <int EPI>
__global__ __launch_bounds__(512, 2) void gemm256(
    const unsigned short* __restrict__ A, const unsigned short* __restrict__ B,
    const float* __restrict__ bias, const int* __restrict__ idx,
    unsigned short* __restrict__ outb, float* __restrict__ outf)
{
  __shared__ __align__(16) unsigned short lds[65536];  // 128 KiB
  const int t = threadIdx.x;
  const int lane = t & 63, wid = t >> 6;
  const int l15 = lane & 15, quad = lane >> 4;
  const int wr = wid >> 2, wc = wid & 3;
  const int bm = blockIdx.x, bn = blockIdx.y;

  // staging: linear LDS dest + inverse-swizzled global source (rule #21)
  const int srow = wid * 8 + (lane >> 3);
  const int scol = ((lane & 7) ^ (lane >> 3)) * 8;
  const unsigned short* gA = A + (size_t)(bm * 256 + srow) * EMBED + scol;
  const unsigned short* gB = B + (size_t)(bn * 256 + srow) * EMBED + scol;

  auto stA = [&](int p, int R0, int kt) {
    const unsigned short* g = gA + (size_t)R0 * EMBED + kt * 64;
    char* d = (char*)lds + p * 32768 + R0 * 128 + wid * 1024;
    gload16(g, d);
    gload16(g + (size_t)64 * EMBED, d + 8192);
  };
  auto stB = [&](int p, int R0, int kt) {
    const unsigned short* g = gB + (size_t)R0 * EMBED + kt * 64;
    char* d = (char*)lds + 65536 + p * 32768 + R0 * 128 + wid * 1024;
    gload16(g, d);
    gload16(g + (size_t)64 * EMBED, d + 8192);
  };

  const int aOff = (wr * 128 + l15) * 64;
  const int bOff = (wc * 64 + l15) * 64;
  const int swz0 = (quad ^ (l15 & 7)) * 8;
  const int swz1 = ((quad + 4) ^ (l15 & 7)) * 8;

  f32x4 acc[8][4];
#pragma unroll
  for (int i = 0; i < 8; ++i)
#pragma unroll
    for (int j = 0; j < 4; ++j) acc[i][j] = (f32x4){0.f, 0.f, 0.f, 0.f};

  // prologue: tile0 (A0,A1,B0,B1) + tile1 (B0,B1); vmcnt(4) keeps tile1's
  // B pair in flight.
  stA(0, 0, 0); stA(0, 128, 0); stB(0, 0, 0); stB(0, 128, 0);
  stB(1, 0, 1); stB(1, 128, 1);
  asm volatile("s_waitcnt vmcnt(4)" ::: "memory");
  BARRIER();

#define MFMA16(m0, m1)                                                       \
  do {                                                                       \
    _Pragma("unroll") for (int nt = 0; nt < 4; ++nt)                         \
        acc[m0][nt] = __builtin_amdgcn_mfma_f32_16x16x32_bf16(               \
            a00, b0[nt], acc[m0][nt], 0, 0, 0);                              \
    _Pragma("unroll") for (int nt = 0; nt < 4; ++nt)                         \
        acc[m1][nt] = __builtin_amdgcn_mfma_f32_16x16x32_bf16(               \
            a10, b0[nt], acc[m1][nt], 0, 0, 0);                              \
    _Pragma("unroll") for (int nt = 0; nt < 4; ++nt)                         \
        acc[m0][nt] = __builtin_amdgcn_mfma_f32_16x16x32_bf16(               \
            a01, b1[nt], acc[m0][nt], 0, 0, 0);                              \
    _Pragma("unroll") for (int nt = 0; nt < 4; ++nt)                         \
        acc[m1][nt] = __builtin_amdgcn_mfma_f32_16x16x32_bf16(               \
            a11, b1[nt], acc[m1][nt], 0, 0, 0);                              \
  } while (0)

  // One K-tile with compile-time parity P. STA/STB/WCNT are literals.
#define TILE(P, KT, STA, STB, WCNT)                                          \
  {                                                                          \
    const unsigned short* Ab = lds + (P) * 16384 + aOff;                     \
    const unsigned short* Bb = lds + 32768 + (P) * 16384 + bOff;             \
    bf16x8 b0[4], b1[4];                                                     \
    { /* phase 0 */                                                          \
      _Pragma("unroll") for (int nt = 0; nt < 4; ++nt) {                     \
        b0[nt] = *(const bf16x8*)(Bb + nt * 1024 + swz0);                    \
        b1[nt] = *(const bf16x8*)(Bb + nt * 1024 + swz1);                    \
      }                                                                      \
      bf16x8 a00 = *(const bf16x8*)(Ab + 0 * 1024 + swz0);                   \
      bf16x8 a01 = *(const bf16x8*)(Ab + 0 * 1024 + swz1);                   \
      bf16x8 a10 = *(const bf16x8*)(Ab + 1 * 1024 + swz0);                   \
      bf16x8 a11 = *(const bf16x8*)(Ab + 1 * 1024 + swz1);                   \
      if (STA) stA((P) ^ 1, 0, (KT) + 1);                                    \
      BARRIER();                                                             \
      __builtin_amdgcn_s_setprio(1);                                         \
      MFMA16(0, 1);                                                          \
      __builtin_amdgcn_s_setprio(0);                                         \
      BARRIER();                                                             \
    }                                                                        \
    { /* phase 1 */                                                          \
      bf16x8 a00 = *(const bf16x8*)(Ab + 2 * 1024 + swz0);                   \
      bf16x8 a01 = *(const bf16x8*)(Ab + 2 * 1024 + swz1);                   \
      bf16x8 a10 = *(const bf16x8*)(Ab + 3 * 1024 + swz0);                   \
      bf16x8 a11 = *(const bf16x8*)(Ab + 3 * 1024 + swz1);                   \
      if (STA) stA((P) ^ 1, 128, (KT) + 1);                                  \
      BARRIER();                                                             \
      __builtin_amdgcn_s_setprio(1);                                         \
      MFMA16(2, 3);                                                          \
      __builtin_amdgcn_s_setprio(0);                                         \
      BARRIER();                                                             \
    }                                                                        \
    { /* phase 2 */                                                          \
      bf16x8 a00 = *(const bf16x8*)(Ab + 4 * 1024 + swz0);                   \
      bf16x8 a01 = *(const bf16x8*)(Ab + 4 * 1024 + swz1);                   \
      bf16x8 a10 = *(const bf16x8*)(Ab + 5 * 1024 + swz0);                   \
      bf16x8 a11 = *(const bf16x8*)(Ab + 5 * 1024 + swz1);                   \
      if (STB) stB((P), 0, (KT) + 2);                                        \
      BARRIER();                                                             \
      __builtin_amdgcn_s_setprio(1);                                         \
      MFMA16(4, 5);                                                          \
      __builtin_amdgcn_s_setprio(0);                                         \
      BARRIER();                                                             \
    }                                                                        \
    { /* phase 3 */                                                          \
      bf16x8 a00 = *(const bf16x8*)(Ab + 6 * 1024 + swz0);                   \
      bf16x8 a01 = *(const bf16x8*)(Ab + 6 * 1024 + swz1);                   \
      bf16x8 a10 = *(const bf16x8*)(Ab + 7 * 1024 + swz0);                   \
      bf16x8 a11 = *(const bf16x8*)(Ab + 7 * 1024 + swz1);                   \
      if (STB) stB((P), 128, (KT) + 2);                                      \
      BARRIER();                                                             \
      __builtin_amdgcn_s_setprio(1);                                         \
      MFMA16(6, 7);                                                          \
      __builtin_amdgcn_s_setprio(0);                                         \
      if ((WCNT) == 4) asm volatile("s_waitcnt vmcnt(4)" ::: "memory");      \
      if ((WCNT) == 0) asm volatile("s_waitcnt vmcnt(0)" ::: "memory");      \
      BARRIER();                                                             \
    }                                                                        \
  }

#pragma unroll 1
  for (int t2 = 0; t2 < 7; ++t2) {
    const int kt = t2 * 2;
    TILE(0, kt, 1, 1, 4);
    TILE(1, kt + 1, 1, 1, 4);
  }
  // tail: tile 14 stages tile 15's A then drains; tile 15 computes clean.
  TILE(0, 14, 1, 0, 0);
  TILE(1, 15, 0, 0, -1);
#undef TILE
#undef MFMA16

  // epilogue
  float bv[4];
#pragma unroll
  for (int nt = 0; nt < 4; ++nt)
    bv[nt] = bias[bn * 256 + wc * 64 + nt * 16 + l15];
  if constexpr (EPI == 0) {
    const int hh = bn * 4 + wc;  // wave's 64-col span == one (part,head) slot
    unsigned short* buf = outb + (size_t)hh * (MTOT * HDIM);
#pragma unroll
    for (int mt = 0; mt < 8; ++mt) {
#pragma unroll
      for (int reg = 0; reg < 4; ++reg) {
        int row = bm * 256 + wr * 128 + mt * 16 + quad * 4 + reg;
        int i = idx[row];  // inv[]
#pragma unroll
        for (int nt = 0; nt < 4; ++nt)
          buf[(size_t)i * HDIM + nt * 16 + l15] =
              f2b(acc[mt][nt][reg] + bv[nt]);
      }
    }
  } else {
    const int col = bn * 256 + wc * 64;
#pragma unroll
    for (int mt = 0; mt < 8; ++mt) {
#pragma unroll
      for (int reg = 0; reg < 4; ++reg) {
        int i = bm * 256 + wr * 128 + mt * 16 + quad * 4 + reg;
        int orow = idx[i];  // kvi[]
        if (orow < LTOT) {
#pragma unroll
          for (int nt = 0; nt < 4; ++nt)
            outf[(size_t)orow * EMBED + col + nt * 16 + l15] =
                acc[mt][nt][reg] + bv[nt];
        }
      }
    }
  }
}

// ---------------------------------------------------------------------------
// rope_qk: in-place RoPE on qkvh head-slots 0..31 (Q scaled by 0.125).
// ---------------------------------------------------------------------------
__global__ __launch_bounds__(256) void rope_qk(
    const float* __restrict__ rope_cos, const float* __restrict__ rope_sin,
    unsigned short* __restrict__ qkvh)
{
  int g = blockIdx.x * 256 + threadIdx.x;
  int dc = g & 3;
  int i  = (g >> 2) & (MTOT - 1);
  int hh = g >> 16;
  unsigned short* p = qkvh + ((size_t)hh * MTOT + i) * HDIM;
  bf16x8 lo = *(const bf16x8*)(p + dc * 8);
  bf16x8 hi = *(const bf16x8*)(p + 32 + dc * 8);
  const float* cp = rope_cos + (size_t)i * HDIM + dc * 8;
  const float* sp = rope_sin + (size_t)i * HDIM + dc * 8;
  float cl[8], ch[8], sl[8], sh[8];
  *(float4*)(cl)     = *(const float4*)(cp);
  *(float4*)(cl + 4) = *(const float4*)(cp + 4);
  *(float4*)(ch)     = *(const float4*)(cp + 32);
  *(float4*)(ch + 4) = *(const float4*)(cp + 36);
  *(float4*)(sl)     = *(const float4*)(sp);
  *(float4*)(sl + 4) = *(const float4*)(sp + 4);
  *(float4*)(sh)     = *(const float4*)(sp + 32);
  *(float4*)(sh + 4) = *(const float4*)(sp + 36);
  const float sc = (hh < 16) ? 0.125f : 1.0f;
  bf16x8 olo, ohi;
#pragma unroll
  for (int j = 0; j < 8; ++j) {
    float a = b2f((unsigned short)lo[j]);
    float b = b2f((unsigned short)hi[j]);
    olo[j] = (short)f2b((a * cl[j] - b * sl[j]) * sc);
    ohi[j] = (short)f2b((b * ch[j] + a * sh[j]) * sc);
  }
  *(bf16x8*)(p + dc * 8) = olo;
  *(bf16x8*)(p + 32 + dc * 8) = ohi;
}

// ---------------------------------------------------------------------------
// cast_w: proj_w fp32 -> bf16, into the (now dead) Q region of qkvh.
// ---------------------------------------------------------------------------
__global__ __launch_bounds__(256) void cast_w(
    const float* __restrict__ w, unsigned short* __restrict__ wb)
{
  int g = blockIdx.x * 256 + threadIdx.x;
  size_t e = (size_t)g * 8;
  float4 a = *(const float4*)(w + e);
  float4 b = *(const float4*)(w + e + 4);
  ushort4 u0, u1;
  u0.x = f2b(a.x); u0.y = f2b(a.y); u0.z = f2b(a.z); u0.w = f2b(a.w);
  u1.x = f2b(b.x); u1.y = f2b(b.y); u1.z = f2b(b.z); u1.w = f2b(b.w);
  *(ushort4*)(wb + e) = u0;
  *(ushort4*)(wb + e + 4) = u1;
}

// ---------------------------------------------------------------------------
// Attention: one block per (window, head). Round-3/4 changes:
//  (a) __launch_bounds__(256,3): was (256,4) which capped the unified RF at
//      128 regs/wave (64 VGPR + 64 AGPR for accO) — suspected spill-to-
//      scratch = the invariant 233 MB phantom HBM write traffic. Cap now
//      ~170 regs/wave.
//  (b) vectorized epilogue: per-wave LDS transpose (reusing sK after a
//      final barrier), each lane stores one 16B bf16x8 (full-line writes)
//      instead of 16 scalar 2B stores.
// Output in window-permuted order (ow); kvi scatter lives in gemm_proj.
// ---------------------------------------------------------------------------
__global__ __launch_bounds__(256, 3) void attn(
    const unsigned short* __restrict__ qkvh,
    unsigned short* __restrict__ ow)
{
  __shared__ __align__(16) unsigned short sK[128 * 64];
  __shared__ __align__(16) unsigned short sV[64 * 128];
  __shared__ __align__(16) unsigned short sP[4][16 * 40];

  const int t = threadIdx.x;
  const int lane = t & 63, wid = t >> 6;
  const int l15 = lane & 15, quad = lane >> 4;
  const int wwin = blockIdx.x >> 4;
  const int h = blockIdx.x & 15;

  const unsigned short* Qh = qkvh + (size_t)h * (MTOT * HDIM);
  const unsigned short* Kh = qkvh + (size_t)(16 + h) * (MTOT * HDIM);
  const unsigned short* Vh = qkvh + (size_t)(32 + h) * (MTOT * HDIM);

  f32x4 accO[4][4];
  float mrow[4][4], lrow[4][4];
#pragma unroll
  for (int qt = 0; qt < 4; ++qt) {
#pragma unroll
    for (int nt = 0; nt < 4; ++nt) accO[qt][nt] = (f32x4){0.f, 0.f, 0.f, 0.f};
#pragma unroll
    for (int reg = 0; reg < 4; ++reg) { mrow[qt][reg] = -1e30f; lrow[qt][reg] = 0.f; }
  }

  bf16x8 qa[4][2];
#pragma unroll
  for (int qt = 0; qt < 4; ++qt) {
    int i = wwin * 256 + wid * 64 + qt * 16 + l15;
    const unsigned short* qp = Qh + (size_t)i * HDIM;
    qa[qt][0] = *(const bf16x8*)(qp + quad * 8);
    qa[qt][1] = *(const bf16x8*)(qp + 32 + quad * 8);
  }

  for (int half = 0; half < 2; ++half) {
    __syncthreads();
    {
      int key = t >> 1, hx = t & 1;
      int i = wwin * 256 + half * 128 + key;
      const unsigned short* kp = Kh + (size_t)i * HDIM + hx * 32;
#pragma unroll
      for (int cc = 0; cc < 4; ++cc) {
        int c = hx * 4 + cc;
        uint4 kv = *(const uint4*)(kp + cc * 8);
        *(uint4*)(sK + key * 64 + ((c ^ (key & 7)) * 8)) = kv;
      }
      const unsigned short* vp = Vh + (size_t)i * HDIM + hx * 32;
      int kc3 = key >> 3, k7 = key & 7;
#pragma unroll
      for (int c = 0; c < 4; ++c) {
        bf16x8 va = *(const bf16x8*)(vp + c * 8);
#pragma unroll
        for (int j = 0; j < 8; ++j) {
          int d = hx * 32 + c * 8 + j;
          sV[d * 128 + ((kc3 ^ (d & 7)) * 8) + k7] = (unsigned short)va[j];
        }
      }
    }
    __syncthreads();

#pragma unroll
    for (int qt = 0; qt < 4; ++qt) {
      f32x4 accS[8];
#pragma unroll
      for (int nt = 0; nt < 8; ++nt) accS[nt] = (f32x4){0.f, 0.f, 0.f, 0.f};
#pragma unroll
      for (int ks = 0; ks < 2; ++ks) {
#pragma unroll
        for (int nt = 0; nt < 8; ++nt) {
          int key = nt * 16 + l15;
          bf16x8 bk = *(const bf16x8*)(
              sK + key * 64 + (((ks * 4 + quad) ^ (key & 7)) * 8));
          accS[nt] = __builtin_amdgcn_mfma_f32_16x16x32_bf16(
              qa[qt][ks], bk, accS[nt], 0, 0, 0);
        }
      }
#pragma unroll
      for (int reg = 0; reg < 4; ++reg) {
        float mx = accS[0][reg];
#pragma unroll
        for (int nt = 1; nt < 8; ++nt) mx = fmaxf(mx, accS[nt][reg]);
#pragma unroll
        for (int off = 1; off < 16; off <<= 1)
          mx = fmaxf(mx, __shfl_xor(mx, off, 64));
        float mold = mrow[qt][reg];
        float mnew = fmaxf(mold, mx);
        float alpha = __expf(mold - mnew);
        mrow[qt][reg] = mnew;
        float ls = 0.f;
#pragma unroll
        for (int nt = 0; nt < 8; ++nt) {
          float p = __expf(accS[nt][reg] - mnew);
          accS[nt][reg] = p;
          ls += p;
        }
#pragma unroll
        for (int off = 1; off < 16; off <<= 1) ls += __shfl_xor(ls, off, 64);
        lrow[qt][reg] = lrow[qt][reg] * alpha + ls;
#pragma unroll
        for (int nt = 0; nt < 4; ++nt) accO[qt][nt][reg] *= alpha;
      }
#pragma unroll
      for (int kc = 0; kc < 4; ++kc) {
#pragma unroll
        for (int nt2 = 0; nt2 < 2; ++nt2) {
#pragma unroll
          for (int reg = 0; reg < 4; ++reg) {
            sP[wid][(quad * 4 + reg) * 40 + nt2 * 16 + l15] =
                f2b(accS[kc * 2 + nt2][reg]);
          }
        }
        bf16x8 pa = *(const bf16x8*)(&sP[wid][l15 * 40 + quad * 8]);
#pragma unroll
        for (int nt = 0; nt < 4; ++nt) {
          int d = nt * 16 + l15;
          bf16x8 bv = *(const bf16x8*)(
              sV + d * 128 + (((kc * 4 + quad) ^ (d & 7)) * 8));
          accO[qt][nt] = __builtin_amdgcn_mfma_f32_16x16x32_bf16(
              pa, bv, accO[qt][nt], 0, 0, 0);
        }
      }
    }
  }

  // ---- vectorized epilogue: per-wave LDS transpose, 16B/lane stores ----
  __syncthreads();                         // all compute done; sK = scratch
  unsigned short* scr = sK + wid * 2048;   // 4 KB per wave, stride-72 rows
  const int rlane = lane >> 3;             // 0..7
  const int clane = (lane & 7) * 8;        // col chunk (shorts)
#pragma unroll
  for (int qt = 0; qt < 4; ++qt) {
#pragma unroll
    for (int reg = 0; reg < 4; ++reg) {
      float invl = 1.0f / lrow[qt][reg];
      int r = quad * 4 + reg;
#pragma unroll
      for (int nt = 0; nt < 4; ++nt)
        scr[r * 72 + nt * 16 + l15] = f2b(accO[qt][nt][reg] * invl);
    }
    // wave-local scratch: compiler orders the LDS ops (same base pointer)
#pragma unroll
    for (int rr = 0; rr < 2; ++rr) {
      int row = rr * 8 + rlane;
      bf16x8 vv = *(const bf16x8*)(scr + row * 72 + clane);
      int i = wwin * 256 + wid * 64 + qt * 16 + row;
      *(bf16x8*)(ow + (size_t)i * EMBED + h * HDIM + clane) = vv;
    }
  }
}

// ---------------------------------------------------------------------------
extern "C" void kernel_launch(void* const* d_in, const int* in_sizes, int n_in,
                              void* d_out, int out_size, void* d_ws, size_t ws_size,
                              hipStream_t stream) {
  const float* x        = (const float*)d_in[0];
  const float* qkv_w    = (const float*)d_in[1];
  const float* qkv_b    = (const float*)d_in[2];
  const float* proj_w   = (const float*)d_in[3];
  const float* proj_b   = (const float*)d_in[4];
  const float* padding  = (const float*)d_in[5];
  const float* rope_cos = (const float*)d_in[6];
  const float* rope_sin = (const float*)d_in[7];
  const int*   kvi      = (const int*)d_in[8];

  // ws layout (134.2 MB, proven safe):
  //   [0, 100.66M):       qkvh — head-major, window-permuted [48][16384][64]
  //                       bf16; Q region doubles as wpb after attn.
  //   [100.66M, +33.55M): xb (cast+gemm_qkv) then ow (attn output,
  //                       window-permuted [16384][1024] bf16, gemm_proj A)
  // d_out scratch: head: wqb (6.3 MB); tail: inv (64 KB int32) — both read
  // only by gemm_qkv, which completes before gemm_proj (stream order).
  unsigned short* qkvh = (unsigned short*)d_ws;
  unsigned short* R    = (unsigned short*)((char*)d_ws +
                            (size_t)MTOT * THREE_EMBED * 2);
  unsigned short* xb = R;
  unsigned short* ow = R;
  unsigned short* wqb = (unsigned short*)d_out;
  unsigned short* wpb = qkvh;  // Q region, dead after attn
  int* inv = (int*)((char*)d_out + (size_t)LTOT * EMBED * 4 - (size_t)MTOT * 4);
  float* out = (float*)d_out;

  cast_inputs<<<4096, 256, 0, stream>>>(x, padding, qkv_w, kvi, xb, wqb, inv);
  gemm256<0><<<dim3(64, 12), 512, 0, stream>>>(xb, wqb, qkv_b, inv, qkvh,
                                               nullptr);
  rope_qk<<<8192, 256, 0, stream>>>(rope_cos, rope_sin, qkvh);
  attn<<<dim3(64 * 16), 256, 0, stream>>>(qkvh, ow);
  cast_w<<<512, 256, 0, stream>>>(proj_w, wpb);
  gemm256<1><<<dim3(64, 4), 512, 0, stream>>>(ow, wpb, proj_b, kvi, nullptr,
                                              out);
}